// Round 20
// baseline (477.916 us; speedup 1.0000x reference)
//
#include <hip/hip_runtime.h>
#include <hip/hip_bf16.h>
#include <math.h>

// Problem constants
#define BB    4
#define TT    1024
#define EE    256
#define HIDD  256
#define LLUT  8
#define HGT   384
#define WID   384
#define HWPX  147456      // 384*384
#define GSZ   33
#define G3    35937       // 33^3
#define NCOL  862488      // L*3*G3

typedef __attribute__((ext_vector_type(8))) short bf16x8;   // 8 bf16 = 4 VGPRs
typedef __attribute__((ext_vector_type(4))) float f32x4;

// fast gelu (tanh form): max abs dev from exact erf-gelu ~1e-3, threshold 2e-2
__device__ __forceinline__ float gelu_f(float x) {
    float s = 1.5957691216057308f * x * (1.0f + 0.044715f * x * x);
    float e = __expf(s);
    return x - x / (e + 1.0f);   // x*sigmoid(s); safe at +-inf
}

__device__ __forceinline__ ushort f2bf(float x) {
    uint u = __float_as_uint(x);
    return (ushort)((u + 0x7FFFu + ((u >> 16) & 1u)) >> 16);   // RNE
}
__device__ __forceinline__ uint pack2bf(float a, float b) {
    return (uint)f2bf(a) | ((uint)f2bf(b) << 16);
}
__device__ __forceinline__ float bf2f_lo(uint u) { return __uint_as_float(u << 16); }
__device__ __forceinline__ float bf2f_hi(uint u) { return __uint_as_float(u & 0xFFFF0000u); }

// conv tiling (shared by MFMA conv kernels)
#define TH2 8
#define TW2 64
#define NTX (WID / TW2)          // 6
#define NTY (HGT / TH2)          // 48
#define NBLK (NTX * NTY * BB)    // 1152
#define CHUNK (NBLK / 8)         // 144
#define HALO_H2 10
#define HALO_H3 11               // in3/in6: taps up to dh=3 (zero-weighted)
#define HALO_W2 66
#define CSTR 40   // padded ushort stride per pixel (80 B)

// wpack layout (ushorts):
//   0..4*9216      : 32->32 convs (rpA, rpB, fuA, fuB)
//   4*9216..6*9216 : 32->3 convs (rp_cout, fu_cout), rows>=3 zero
//   55296..58368   : 6->32 conv (fu_cin), k=tap*8+slot, K=96 (3 mfma)
//   58368..61440   : 3->32 conv (rp_cin), same k-map, slots 3..7 zero
#define WPK_IN6 55296
#define WPK_IN3 58368

// ---------------------------------------------------------------------------
// K-1: pack MFMA A-fragment tables (lane-linear bf16).
// ---------------------------------------------------------------------------
__global__ __launch_bounds__(256) void pack_wconv_kernel(
    const float* __restrict__ w0, const float* __restrict__ w1,
    const float* __restrict__ w2, const float* __restrict__ w3,
    const float* __restrict__ c0w, const float* __restrict__ c1w,
    const float* __restrict__ w6, const float* __restrict__ w7,
    ushort* __restrict__ wpk)
{
    const int layer = blockIdx.x;
    if (layer < 6) {
        const float* w = (layer == 0) ? w0 : (layer == 1) ? w1 :
                         (layer == 2) ? w2 : (layer == 3) ? w3 :
                         (layer == 4) ? c0w : c1w;
        const bool small = (layer >= 4);
        ushort* dst = wpk + layer * 9216;
        for (int i = threadIdx.x; i < 9216; i += 256) {
            const int j    = i & 7;
            const int lane = (i >> 3) & 63;
            const int half = (i >> 9) & 1;
            const int tap  = i >> 10;
            const int co = half * 16 + (lane & 15);
            const int ci = (lane >> 4) * 8 + j;
            float v = 0.f;
            if (!small || co < 3) v = w[co * 288 + ci * 9 + tap];
            dst[i] = f2bf(v);
        }
    } else {
        // layers 6 (in6) / 7 (in3): k = tap*8 + slot, K=96 (3 mfma x 2 halves)
        const bool is6 = (layer == 6);
        ushort* dst = wpk + (is6 ? WPK_IN6 : WPK_IN3);
        for (int i = threadIdx.x; i < 3072; i += 256) {
            const int j    = i & 7;
            const int lane = (i >> 3) & 63;
            const int c6   = i >> 9;          // 0..5
            const int m = c6 >> 1, half = c6 & 1;
            const int co = half * 16 + (lane & 15);
            const int k  = m * 32 + (lane >> 4) * 8 + j;
            const int tap = k >> 3, slot = k & 7;
            float v = 0.f;
            if (tap < 9) {
                if (is6) {
                    int ci = (slot < 3) ? slot : ((slot >= 4 && slot < 7) ? slot - 1 : -1);
                    if (ci >= 0) v = w6[co * 54 + ci * 9 + tap];
                } else {
                    if (slot < 3) v = w7[co * 27 + slot * 9 + tap];
                }
            }
            dst[i] = f2bf(v);
        }
    }
}

// ---------------------------------------------------------------------------
// K0: embedding-mean partial sums. grid (64, B).
// ---------------------------------------------------------------------------
__global__ __launch_bounds__(256) void emb_partial_kernel(
    const int* __restrict__ tokens, const float* __restrict__ emb,
    float* __restrict__ partial)
{
    const int s = blockIdx.x, b = blockIdx.y, tid = threadIdx.x;
    const int* tok = tokens + b * TT + s * 16;
    float acc = 0.f;
#pragma unroll
    for (int t = 0; t < 16; ++t) acc += emb[tok[t] * EE + tid];
    partial[(b * 64 + s) * EE + tid] = acc;
}

// ---------------------------------------------------------------------------
// K1: fused token head, latency-parallel.
// ---------------------------------------------------------------------------
__global__ __launch_bounds__(1024) void mlp_head_kernel(
    const float* __restrict__ partial,
    const float* __restrict__ aw1, const float* __restrict__ ab1,
    const float* __restrict__ aw2, const float* __restrict__ ab2,
    const float* __restrict__ lw1, const float* __restrict__ lb1,
    const float* __restrict__ gw1, const float* __restrict__ gb1,
    const float* __restrict__ gw2, const float* __restrict__ gb2,
    float* __restrict__ h3_out, float* __restrict__ lw_out)
{
    const int b = blockIdx.x;
    const int tid = threadIdx.x;
    const int o = tid & 255;
    const int q = tid >> 8;
    __shared__ float tf[256], h1[256], tf2s[256], h4[64], lg[8];
    __shared__ float red[4][256];

    {
        float acc = 0.f;
#pragma unroll
        for (int s = 0; s < 16; ++s)
            acc += partial[(b * 64 + q * 16 + s) * EE + o];
        red[q][o] = acc;
    }
    __syncthreads();
    if (tid < 256)
        tf[tid] = (red[0][tid] + red[1][tid] + red[2][tid] + red[3][tid]) * (1.0f / TT);
    __syncthreads();

    {
        float s = 0.f;
#pragma unroll 8
        for (int j = 0; j < 64; ++j) {
            const int k = (q << 6) + j;
            s += tf[k] * aw1[k * HIDD + o];
        }
        red[q][o] = s;
    }
    __syncthreads();
    if (tid < 256)
        h1[tid] = gelu_f(red[0][tid] + red[1][tid] + red[2][tid] + red[3][tid] + ab1[tid]);
    __syncthreads();

    {
        float s = 0.f;
#pragma unroll 8
        for (int j = 0; j < 64; ++j) {
            const int k = (q << 6) + j;
            s += h1[k] * aw2[k * HIDD + o];
        }
        red[q][o] = s;
    }
    __syncthreads();
    if (tid < 256)
        tf2s[tid] = red[0][tid] + red[1][tid] + red[2][tid] + red[3][tid] + ab2[tid];
    __syncthreads();

    {
        float s = 0.f;
#pragma unroll 8
        for (int j = 0; j < 64; ++j) {
            const int k = (q << 6) + j;
            s += tf2s[k] * lw1[k * HIDD + o];
        }
        red[q][o] = s;
    }
    __syncthreads();
    if (tid < 256)
        h3_out[b * HIDD + tid] =
            gelu_f(red[0][tid] + red[1][tid] + red[2][tid] + red[3][tid] + lb1[tid]);
    __syncthreads();

    {
        const int o64 = tid & 63, q16 = tid >> 6;
        float s = 0.f;
#pragma unroll
        for (int j = 0; j < 16; ++j) {
            const int k = q16 * 16 + j;
            s += tf2s[k] * gw1[k * 64 + o64];
        }
        ((float*)red)[q16 * 64 + o64] = s;
    }
    __syncthreads();
    if (tid < 64) {
        float s = gb1[tid];
#pragma unroll
        for (int r = 0; r < 16; ++r) s += ((float*)red)[r * 64 + tid];
        h4[tid] = gelu_f(s);
    }
    __syncthreads();

    if (tid < 8) {
        float s = gb2[tid];
#pragma unroll 8
        for (int k = 0; k < 64; ++k) s += h4[k] * gw2[k * LLUT + tid];
        lg[tid] = s;
    }
    __syncthreads();
    if (tid == 0) {
        float m = lg[0];
        for (int i = 1; i < LLUT; ++i) m = fmaxf(m, lg[i]);
        float ssum = 0.f, ex[LLUT];
        for (int i = 0; i < LLUT; ++i) { ex[i] = expf(lg[i] - m); ssum += ex[i]; }
        for (int i = 0; i < LLUT; ++i) lw_out[b * LLUT + i] = ex[i] / ssum;
    }
}

// ---------------------------------------------------------------------------
// K2 v3: l-split fused LUT-GEMM. grid (422, 2): blockIdx.y = l-half; each
// half reads ONLY its 4 l-streams of w2 (no duplicate traffic) and writes
// its lw-weighted partial. Doubles TLP (6.6 -> 13 waves/CU) for the 883 MB
// latency-critical stream; acc VGPRs halve -> more resident waves.
// ---------------------------------------------------------------------------
__global__ __launch_bounds__(256) void lut_fused_kernel(
    const float* __restrict__ h3, const float* __restrict__ lwv,
    const float* __restrict__ w2, const float* __restrict__ b2,
    float* __restrict__ lpart)
{
    __shared__ float h[BB * HIDD];
    __shared__ float lws[BB * LLUT];
    const int tid = threadIdx.x;
    for (int i = tid; i < BB * HIDD; i += 256) h[i] = h3[i];
    if (tid < BB * LLUT) lws[tid] = lwv[tid];
    __syncthreads();

    const int idx = blockIdx.x * 256 + tid;
    if (idx >= 3 * G3) return;
    const int half = blockIdx.y;           // 0/1
    const int l0 = half * 4;
    const int c = idx / G3, v = idx - c * G3;

    float acc[BB][4];
#pragma unroll
    for (int b = 0; b < BB; ++b)
#pragma unroll
        for (int l = 0; l < 4; ++l) acc[b][l] = 0.f;

    const float* wbase = w2 + (long)c * G3 + v + (long)l0 * 3 * G3;
#pragma unroll 4
    for (int k = 0; k < HIDD; ++k) {
        const float* row = wbase + (long)k * NCOL;
        float wl[4];
#pragma unroll
        for (int l = 0; l < 4; ++l) wl[l] = row[(long)l * 3 * G3];
#pragma unroll
        for (int b = 0; b < BB; ++b) {
            const float hb = h[b * HIDD + k];
#pragma unroll
            for (int l = 0; l < 4; ++l) acc[b][l] += wl[l] * hb;
        }
    }

    float bb[4];
#pragma unroll
    for (int l = 0; l < 4; ++l) bb[l] = b2[(long)((l0 + l) * 3 + c) * G3 + v];

#pragma unroll
    for (int b = 0; b < BB; ++b) {
        float s = 0.f;
#pragma unroll
        for (int l = 0; l < 4; ++l)
            s += lws[b * LLUT + l0 + l] * (acc[b][l] + bb[l]);
        lpart[((long)half * BB * 3 + b * 3 + c) * G3 + v] = s;
    }
}

// ---------------------------------------------------------------------------
// K2b: combine the two l-half partials -> clut. 1.7 MB output, ~1 us.
// ---------------------------------------------------------------------------
__global__ __launch_bounds__(256) void lut_combine_kernel(
    const float* __restrict__ lpart, float* __restrict__ clut)
{
    const int i = blockIdx.x * 256 + threadIdx.x;
    if (i < BB * 3 * G3) clut[i] = lpart[i] + lpart[BB * 3 * G3 + i];
}

// ---------------------------------------------------------------------------
// K5: MFMA 3->32 conv. img staged as bf16 [11][66][8] (slots 0..2 = ch,
// 3..7 = 0). k = tap*8+slot, 3 mfma x 2 halves; each B-frag = one b128.
// ---------------------------------------------------------------------------
__global__ __launch_bounds__(512) void conv_in3_mfma(
    const float* __restrict__ img, const ushort* __restrict__ wpk3,
    const float* __restrict__ bias, ushort* __restrict__ out)
{
    __shared__ ushort ihalo[HALO_H3 * HALO_W2 * 8];   // 11616 B
    __shared__ float s_bias[32];

    const int tid = threadIdx.x;
    const int bid = blockIdx.x;
    const int t   = (bid & 7) * CHUNK + (bid >> 3);
    const int tx  = t % NTX;
    const int rem = t / NTX;
    const int ty  = rem % NTY;
    const int b   = rem / NTY;
    const int h0 = ty * TH2;
    const int w0 = tx * TW2;

    if (tid < 32) s_bias[tid] = bias[tid];

    const float* imb = img + (long)b * 3 * HWPX;
    for (int i = tid; i < HALO_H3 * HALO_W2; i += 512) {
        const int row = i / HALO_W2, px = i - row * HALO_W2;
        const int gh = h0 + row - 1, gw = w0 + px - 1;
        float c0v = 0.f, c1v = 0.f, c2v = 0.f;
        if (gh >= 0 && gh < HGT && gw >= 0 && gw < WID) {
            const int p = gh * WID + gw;
            c0v = imb[p]; c1v = imb[HWPX + p]; c2v = imb[2 * HWPX + p];
        }
        uint4 u; u.x = pack2bf(c0v, c1v); u.y = pack2bf(c2v, 0.f);
        u.z = 0u; u.w = 0u;
        *(uint4*)(&ihalo[i * 8]) = u;
    }
    __syncthreads();

    const int lane = tid & 63, wid = tid >> 6;
    const int l15 = lane & 15, kg = lane >> 4;
    const int r = wid;
    const ushort* wl3 = wpk3 + lane * 8;

    f32x4 acc[4][2];
#pragma unroll
    for (int f = 0; f < 4; ++f)
#pragma unroll
        for (int cf = 0; cf < 2; ++cf)
            acc[f][cf] = (f32x4){0.f, 0.f, 0.f, 0.f};

#pragma unroll
    for (int m = 0; m < 3; ++m) {
        const int tap = m * 4 + kg;            // 0..11 (taps>=9 zero-weighted)
        const int dh = tap / 3, dwp = tap - 3 * (tap / 3);
        const bf16x8 a0 = *(const bf16x8*)(wl3 + (m * 2 + 0) * 512);
        const bf16x8 a1 = *(const bf16x8*)(wl3 + (m * 2 + 1) * 512);
#pragma unroll
        for (int f = 0; f < 4; ++f) {
            const int c0 = f * 16;
            const bf16x8 bv = *(const bf16x8*)(
                &ihalo[((r + dh) * HALO_W2 + (c0 + dwp + l15)) * 8]);
            acc[f][0] = __builtin_amdgcn_mfma_f32_16x16x32_bf16(a0, bv, acc[f][0], 0, 0, 0);
            acc[f][1] = __builtin_amdgcn_mfma_f32_16x16x32_bf16(a1, bv, acc[f][1], 0, 0, 0);
        }
    }

#pragma unroll
    for (int f = 0; f < 4; ++f) {
        const int c0 = f * 16;
        const long gpx = (long)b * HWPX + (long)(h0 + r) * WID + (w0 + c0 + l15);
#pragma unroll
        for (int cf = 0; cf < 2; ++cf) {
            const int co0 = cf * 16 + kg * 4;
            const float4 bv4 = *(const float4*)(&s_bias[co0]);
            uint2 o;
            o.x = pack2bf(gelu_f(acc[f][cf][0] + bv4.x), gelu_f(acc[f][cf][1] + bv4.y));
            o.y = pack2bf(gelu_f(acc[f][cf][2] + bv4.z), gelu_f(acc[f][cf][3] + bv4.w));
            *(uint2*)(out + gpx * 32 + co0) = o;
        }
    }
}

// ---------------------------------------------------------------------------
// K6: MFMA 32->32 conv (r14 measured-best structure).
// ---------------------------------------------------------------------------
template <bool HAS_RES>
__global__ __launch_bounds__(512, 6) void conv32_mfma(
    const ushort* __restrict__ in, const ushort* __restrict__ res,
    const ushort* __restrict__ wpk, const float* __restrict__ bias,
    const float* __restrict__ bn_g, const float* __restrict__ bn_bt,
    ushort* __restrict__ out)
{
    __shared__ ushort halo[HALO_H2 * HALO_W2 * CSTR];   // 52800 B
    __shared__ float s_scale[32], s_shift[32];

    const int tid = threadIdx.x;
    const int bid = blockIdx.x;
    const int t   = (bid & 7) * CHUNK + (bid >> 3);
    const int tx  = t % NTX;
    const int rem = t / NTX;
    const int ty  = rem % NTY;
    const int b   = rem / NTY;
    const int h0 = ty * TH2;
    const int w0 = tx * TW2;

    if (tid < 32) {
        float sg = bn_g[tid] * 0.9999950000375f;   // g*(1+1e-5)^-0.5
        s_scale[tid] = sg;
        s_shift[tid] = bias[tid] * sg + bn_bt[tid];
    }

    const ushort* inb = in + (long)b * HWPX * 32;
    for (int i = tid; i < HALO_H2 * HALO_W2 * 4; i += 512) {
        const int row = i / (HALO_W2 * 4);
        const int rem2 = i - row * (HALO_W2 * 4);
        const int px = rem2 >> 2, q = rem2 & 3;
        const int gh = h0 + row - 1, gw = w0 + px - 1;
        uint4 v = make_uint4(0u, 0u, 0u, 0u);
        if (gh >= 0 && gh < HGT && gw >= 0 && gw < WID)
            v = *(const uint4*)(inb + ((long)gh * WID + gw) * 32 + q * 8);
        *(uint4*)(&halo[(row * HALO_W2 + px) * CSTR + q * 8]) = v;
    }
    __syncthreads();

    const int lane = tid & 63, wid = tid >> 6;
    const int l15 = lane & 15, kg = lane >> 4;
    const int r = wid;
    const ushort* wlane = wpk + lane * 8;

    f32x4 acc[4][2];
#pragma unroll
    for (int f = 0; f < 4; ++f)
#pragma unroll
        for (int cf = 0; cf < 2; ++cf)
            acc[f][cf] = (f32x4){0.f, 0.f, 0.f, 0.f};

#pragma unroll
    for (int tap = 0; tap < 9; ++tap) {
        const int dh = tap / 3, dw = tap - dh * 3;
        const bf16x8 a0 = *(const bf16x8*)(wlane + (tap * 2 + 0) * 512);
        const bf16x8 a1 = *(const bf16x8*)(wlane + (tap * 2 + 1) * 512);
#pragma unroll
        for (int f = 0; f < 4; ++f) {
            const int c0 = f * 16;
            const bf16x8 bfv = *(const bf16x8*)(
                &halo[((r + dh) * HALO_W2 + (c0 + dw + l15)) * CSTR + kg * 8]);
            acc[f][0] = __builtin_amdgcn_mfma_f32_16x16x32_bf16(a0, bfv, acc[f][0], 0, 0, 0);
            acc[f][1] = __builtin_amdgcn_mfma_f32_16x16x32_bf16(a1, bfv, acc[f][1], 0, 0, 0);
        }
    }

#pragma unroll
    for (int f = 0; f < 4; ++f) {
        const int c0 = f * 16;
        const long gpx = (long)b * HWPX + (long)(h0 + r) * WID + (w0 + c0 + l15);
#pragma unroll
        for (int cf = 0; cf < 2; ++cf) {
            const int co0 = cf * 16 + kg * 4;
            const float4 sc = *(const float4*)(&s_scale[co0]);
            const float4 sh = *(const float4*)(&s_shift[co0]);
            float v0 = acc[f][cf][0] * sc.x + sh.x;
            float v1 = acc[f][cf][1] * sc.y + sh.y;
            float v2 = acc[f][cf][2] * sc.z + sh.z;
            float v3 = acc[f][cf][3] * sc.w + sh.w;
            if (HAS_RES) {
                const uint2 rv = *(const uint2*)(res + gpx * 32 + co0);
                v0 += bf2f_lo(rv.x); v1 += bf2f_hi(rv.x);
                v2 += bf2f_lo(rv.y); v3 += bf2f_hi(rv.y);
            }
            uint2 o;
            o.x = pack2bf(gelu_f(v0), gelu_f(v1));
            o.y = pack2bf(gelu_f(v2), gelu_f(v3));
            *(uint2*)(out + gpx * 32 + co0) = o;
        }
    }
}

// ---------------------------------------------------------------------------
// K7: MFMA 32->3 conv. FINAL=false additionally computes the trilinear LUT
// apply for its 512 tile pixels (1 px/thread) -> comb slots 0..3; conv
// result -> comb slots 4..7. FINAL=true: conv + img -> fp32 NCHW d_out.
// ---------------------------------------------------------------------------
template <bool FINAL>
__global__ __launch_bounds__(512, 4) void conv_out3_mfma(
    const ushort* __restrict__ in, const ushort* __restrict__ wpk,
    const float* __restrict__ bias, const float* __restrict__ img,
    float* __restrict__ outp, ushort* __restrict__ comb,
    const float* __restrict__ clut, const float* __restrict__ recon)
{
    __shared__ ushort halo[HALO_H2 * HALO_W2 * CSTR];   // 52800 B

    const int tid = threadIdx.x;
    const int bid = blockIdx.x;
    const int t   = (bid & 7) * CHUNK + (bid >> 3);
    const int tx  = t % NTX;
    const int rem = t / NTX;
    const int ty  = rem % NTY;
    const int b   = rem / NTY;
    const int h0 = ty * TH2;
    const int w0 = tx * TW2;

    const ushort* inb = in + (long)b * HWPX * 32;
    for (int i = tid; i < HALO_H2 * HALO_W2 * 4; i += 512) {
        const int row = i / (HALO_W2 * 4);
        const int rem2 = i - row * (HALO_W2 * 4);
        const int px = rem2 >> 2, q = rem2 & 3;
        const int gh = h0 + row - 1, gw = w0 + px - 1;
        uint4 v = make_uint4(0u, 0u, 0u, 0u);
        if (gh >= 0 && gh < HGT && gw >= 0 && gw < WID)
            v = *(const uint4*)(inb + ((long)gh * WID + gw) * 32 + q * 8);
        *(uint4*)(&halo[(row * HALO_W2 + px) * CSTR + q * 8]) = v;
    }
    __syncthreads();

    const int lane = tid & 63, wid = tid >> 6;
    const int l15 = lane & 15, kg = lane >> 4;
    const int r = wid;
    const ushort* wlane = wpk + lane * 8;

    f32x4 acc[4];
#pragma unroll
    for (int f = 0; f < 4; ++f) acc[f] = (f32x4){0.f, 0.f, 0.f, 0.f};

#pragma unroll
    for (int tap = 0; tap < 9; ++tap) {
        const int dh = tap / 3, dw = tap - dh * 3;
        const bf16x8 a0 = *(const bf16x8*)(wlane + (tap * 2 + 0) * 512);
#pragma unroll
        for (int f = 0; f < 4; ++f) {
            const int c0 = f * 16;
            const bf16x8 bfv = *(const bf16x8*)(
                &halo[((r + dh) * HALO_W2 + (c0 + dw + l15)) * CSTR + kg * 8]);
            acc[f] = __builtin_amdgcn_mfma_f32_16x16x32_bf16(a0, bfv, acc[f], 0, 0, 0);
        }
    }

    if (kg == 0) {   // rows 0..2 of D valid
        const float b0 = bias[0], b1 = bias[1], b2v = bias[2];
#pragma unroll
        for (int f = 0; f < 4; ++f) {
            const int p = (h0 + r) * WID + (w0 + f * 16 + l15);
            const long gpx = (long)b * HWPX + p;
            float v0 = acc[f][0] + b0;
            float v1 = acc[f][1] + b1;
            float v2 = acc[f][2] + b2v;
            if (FINAL) {
                outp[(long)(b * 3 + 0) * HWPX + p] = v0 + img[(long)(b * 3 + 0) * HWPX + p];
                outp[(long)(b * 3 + 1) * HWPX + p] = v1 + img[(long)(b * 3 + 1) * HWPX + p];
                outp[(long)(b * 3 + 2) * HWPX + p] = v2 + img[(long)(b * 3 + 2) * HWPX + p];
            } else {
                uint2 u;
                u.x = pack2bf(v0, v1);
                u.y = pack2bf(v2, 0.f);
                *(uint2*)(comb + gpx * 8 + 4) = u;
            }
        }
    }

    if (!FINAL) {
        // fused trilinear LUT apply: 1 px/thread over the 8x64 tile
        const int row = tid >> 6, col = tid & 63;
        const int p = (h0 + row) * WID + (w0 + col);
        const float* rc = recon + (long)b * 3 * HWPX;
        float cr = fminf(fmaxf(rc[p] * 32.f, 0.f), 32.f);
        float cg = fminf(fmaxf(rc[HWPX + p] * 32.f, 0.f), 32.f);
        float cb = fminf(fmaxf(rc[2 * HWPX + p] * 32.f, 0.f), 32.f);
        float fr = fminf(floorf(cr), 31.f);
        float fg = fminf(floorf(cg), 31.f);
        float fb = fminf(floorf(cb), 31.f);
        float tr = cr - fr, tg = cg - fg, tb_ = cb - fb;
        int idx = (((int)fr * GSZ + (int)fg) * GSZ + (int)fb);
        float c[3];
#pragma unroll
        for (int ch = 0; ch < 3; ++ch) {
            const float* lut = clut + (long)(b * 3 + ch) * G3;
            float v000 = lut[idx],                  v001 = lut[idx + 1];
            float v010 = lut[idx + GSZ],            v011 = lut[idx + GSZ + 1];
            float v100 = lut[idx + GSZ * GSZ],      v101 = lut[idx + GSZ * GSZ + 1];
            float v110 = lut[idx + GSZ * GSZ + GSZ], v111 = lut[idx + GSZ * GSZ + GSZ + 1];
            float c00 = v000 + (v001 - v000) * tb_;
            float c01 = v010 + (v011 - v010) * tb_;
            float c10 = v100 + (v101 - v100) * tb_;
            float c11 = v110 + (v111 - v110) * tb_;
            float c0 = c00 + (c01 - c00) * tg;
            float c1 = c10 + (c11 - c10) * tg;
            c[ch] = c0 + (c1 - c0) * tr;
        }
        uint2 u;
        u.x = pack2bf(c[0], c[1]);
        u.y = pack2bf(c[2], 0.f);
        *(uint2*)(comb + ((long)b * HWPX + p) * 8) = u;
    }
}

// ---------------------------------------------------------------------------
// K8: MFMA 6->32 conv. comb bf16 [px][8] staged to [11][66][8] LDS.
// k = tap*8+slot (K=96, 3 mfma x 2 halves); each B-frag = one b128 read.
// ---------------------------------------------------------------------------
__global__ __launch_bounds__(512) void conv_in6_mfma(
    const ushort* __restrict__ comb, const ushort* __restrict__ wpk6,
    const float* __restrict__ bias, ushort* __restrict__ out)
{
    __shared__ ushort chalo[HALO_H3 * HALO_W2 * 8];   // 11616 B
    __shared__ float s_bias[32];

    const int tid = threadIdx.x;
    const int bid = blockIdx.x;
    const int t   = (bid & 7) * CHUNK + (bid >> 3);
    const int tx  = t % NTX;
    const int rem = t / NTX;
    const int ty  = rem % NTY;
    const int b   = rem / NTY;
    const int h0 = ty * TH2;
    const int w0 = tx * TW2;

    if (tid < 32) s_bias[tid] = bias[tid];

    const ushort* cb = comb + (long)b * HWPX * 8;
    for (int i = tid; i < HALO_H3 * HALO_W2; i += 512) {
        const int row = i / HALO_W2, px = i - row * HALO_W2;
        const int gh = h0 + row - 1, gw = w0 + px - 1;
        uint4 v = make_uint4(0u, 0u, 0u, 0u);
        if (gh >= 0 && gh < HGT && gw >= 0 && gw < WID)
            v = *(const uint4*)(cb + ((long)gh * WID + gw) * 8);
        *(uint4*)(&chalo[i * 8]) = v;
    }
    __syncthreads();

    const int lane = tid & 63, wid = tid >> 6;
    const int l15 = lane & 15, kg = lane >> 4;
    const int r = wid;
    const ushort* wl6 = wpk6 + lane * 8;

    f32x4 acc[4][2];
#pragma unroll
    for (int f = 0; f < 4; ++f)
#pragma unroll
        for (int cf = 0; cf < 2; ++cf)
            acc[f][cf] = (f32x4){0.f, 0.f, 0.f, 0.f};

#pragma unroll
    for (int m = 0; m < 3; ++m) {
        const int tap = m * 4 + kg;            // 0..11 (taps>=9 zero-weighted)
        const int dh = tap / 3, dwp = tap - 3 * (tap / 3);
        const bf16x8 a0 = *(const bf16x8*)(wl6 + (m * 2 + 0) * 512);
        const bf16x8 a1 = *(const bf16x8*)(wl6 + (m * 2 + 1) * 512);
#pragma unroll
        for (int f = 0; f < 4; ++f) {
            const int c0 = f * 16;
            const bf16x8 bv = *(const bf16x8*)(
                &chalo[((r + dh) * HALO_W2 + (c0 + dwp + l15)) * 8]);
            acc[f][0] = __builtin_amdgcn_mfma_f32_16x16x32_bf16(a0, bv, acc[f][0], 0, 0, 0);
            acc[f][1] = __builtin_amdgcn_mfma_f32_16x16x32_bf16(a1, bv, acc[f][1], 0, 0, 0);
        }
    }

#pragma unroll
    for (int f = 0; f < 4; ++f) {
        const int c0 = f * 16;
        const long gpx = (long)b * HWPX + (long)(h0 + r) * WID + (w0 + c0 + l15);
#pragma unroll
        for (int cf = 0; cf < 2; ++cf) {
            const int co0 = cf * 16 + kg * 4;
            const float4 bv4 = *(const float4*)(&s_bias[co0]);
            uint2 o;
            o.x = pack2bf(gelu_f(acc[f][cf][0] + bv4.x), gelu_f(acc[f][cf][1] + bv4.y));
            o.y = pack2bf(gelu_f(acc[f][cf][2] + bv4.z), gelu_f(acc[f][cf][3] + bv4.w));
            *(uint2*)(out + gpx * 32 + co0) = o;
        }
    }
}

// ---------------------------------------------------------------------------
extern "C" void kernel_launch(void* const* d_in, const int* in_sizes, int n_in,
                              void* d_out, int out_size, void* d_ws, size_t ws_size,
                              hipStream_t stream)
{
    const int*   tokens  = (const int*)d_in[0];
    const float* img     = (const float*)d_in[1];
    const float* recon   = (const float*)d_in[2];
    const float* emb     = (const float*)d_in[3];
    const float* agg_w1  = (const float*)d_in[4];
    const float* agg_b1  = (const float*)d_in[5];
    const float* agg_w2  = (const float*)d_in[6];
    const float* agg_b2  = (const float*)d_in[7];
    const float* lut_w1  = (const float*)d_in[8];
    const float* lut_b1  = (const float*)d_in[9];
    const float* lut_w2  = (const float*)d_in[10];
    const float* lut_b2  = (const float*)d_in[11];
    const float* wg_w1   = (const float*)d_in[12];
    const float* wg_b1   = (const float*)d_in[13];
    const float* wg_w2   = (const float*)d_in[14];
    const float* wg_b2   = (const float*)d_in[15];
    const float* rp_cin_w = (const float*)d_in[16];
    const float* rp_cin_b = (const float*)d_in[17];
    const float* rp_rbA_w = (const float*)d_in[18];
    const float* rp_rbA_b = (const float*)d_in[19];
    const float* rp_rbA_g = (const float*)d_in[20];
    const float* rp_rbA_bt= (const float*)d_in[21];
    const float* rp_rbB_w = (const float*)d_in[22];
    const float* rp_rbB_b = (const float*)d_in[23];
    const float* rp_rbB_g = (const float*)d_in[24];
    const float* rp_rbB_bt= (const float*)d_in[25];
    const float* rp_cout_w= (const float*)d_in[26];
    const float* rp_cout_b= (const float*)d_in[27];
    const float* fu_cin_w = (const float*)d_in[28];
    const float* fu_cin_b = (const float*)d_in[29];
    const float* fu_rbA_w = (const float*)d_in[30];
    const float* fu_rbA_b = (const float*)d_in[31];
    const float* fu_rbA_g = (const float*)d_in[32];
    const float* fu_rbA_bt= (const float*)d_in[33];
    const float* fu_rbB_w = (const float*)d_in[34];
    const float* fu_rbB_b = (const float*)d_in[35];
    const float* fu_rbB_g = (const float*)d_in[36];
    const float* fu_rbB_bt= (const float*)d_in[37];
    const float* fu_cout_w= (const float*)d_in[38];
    const float* fu_cout_b= (const float*)d_in[39];

    float* ws = (float*)d_ws;
    float*  h3      = ws;                       // 1024
    float*  lwv     = ws + 1024;                // 32
    float*  partial = ws + 2048;                // 65536
    float*  clut    = ws + 69632;               // 431244
    ushort* wpack   = (ushort*)(ws + 524288);   // 61440 ushorts (30720 fl)
    float*  lpart   = ws + 557056;              // 862488 (2 x BB*3*G3)
    ushort* comb    = (ushort*)(ws + 1441792);  // 4*HWPX*8 ushorts (bf16)
    ushort* act0    = (ushort*)(ws + 3932160);  // 18874368 ushorts
    ushort* act1    = (ushort*)(ws + 13369344);
    ushort* act2    = (ushort*)(ws + 22806528);
    float*  outp    = (float*)d_out;

    // pack all MFMA A-fragment tables
    pack_wconv_kernel<<<dim3(8), dim3(256), 0, stream>>>(
        rp_rbA_w, rp_rbB_w, fu_rbA_w, fu_rbB_w, rp_cout_w, fu_cout_w,
        fu_cin_w, rp_cin_w, wpack);

    // token head
    emb_partial_kernel<<<dim3(64, BB), dim3(256), 0, stream>>>(tokens, emb, partial);
    mlp_head_kernel<<<dim3(BB), dim3(1024), 0, stream>>>(
        partial, agg_w1, agg_b1, agg_w2, agg_b2,
        lut_w1, lut_b1, wg_w1, wg_b1, wg_w2, wg_b2, h3, lwv);

    // l-split fused LUT GEMM (2x TLP) + tiny combine -> clut
    lut_fused_kernel<<<dim3((3 * G3 + 255) / 256, 2), dim3(256), 0, stream>>>(
        h3, lwv, lut_w2, lut_b2, lpart);
    lut_combine_kernel<<<dim3((BB * 3 * G3 + 255) / 256), dim3(256), 0, stream>>>(
        lpart, clut);

    const dim3 gm(NBLK), bm(512);

    // proc branch: img -> act0 -> act1 -> act2
    conv_in3_mfma<<<gm, bm, 0, stream>>>(img, wpack + WPK_IN3, rp_cin_b, act0);
    conv32_mfma<false><<<gm, bm, 0, stream>>>(
        act0, nullptr, wpack + 0 * 9216, rp_rbA_b, rp_rbA_g, rp_rbA_bt, act1);
    conv32_mfma<true><<<gm, bm, 0, stream>>>(
        act1, act0, wpack + 1 * 9216, rp_rbB_b, rp_rbB_g, rp_rbB_bt, act2);

    // proc 32->3 (MFMA) + fused LUT apply -> comb
    conv_out3_mfma<false><<<gm, bm, 0, stream>>>(
        act2, wpack + 4 * 9216, rp_cout_b, nullptr, nullptr, comb, clut, recon);

    // fuse branch: comb -> act0 -> act1 -> act2 -> d_out (+img)
    conv_in6_mfma<<<gm, bm, 0, stream>>>(comb, wpack + WPK_IN6, fu_cin_b, act0);
    conv32_mfma<false><<<gm, bm, 0, stream>>>(
        act0, nullptr, wpack + 2 * 9216, fu_rbA_b, fu_rbA_g, fu_rbA_bt, act1);
    conv32_mfma<true><<<gm, bm, 0, stream>>>(
        act1, act0, wpack + 3 * 9216, fu_rbB_b, fu_rbB_g, fu_rbB_bt, act2);
    conv_out3_mfma<true><<<gm, bm, 0, stream>>>(
        act2, wpack + 5 * 9216, fu_cout_b, img, outp, nullptr, nullptr, nullptr);
}

// Round 21
// 467.602 us; speedup vs baseline: 1.0221x; 1.0221x over previous
//
#include <hip/hip_runtime.h>
#include <hip/hip_bf16.h>
#include <math.h>

// Problem constants
#define BB    4
#define TT    1024
#define EE    256
#define HIDD  256
#define LLUT  8
#define HGT   384
#define WID   384
#define HWPX  147456      // 384*384
#define GSZ   33
#define G3    35937       // 33^3
#define NCOL  862488      // L*3*G3

typedef __attribute__((ext_vector_type(8))) short bf16x8;   // 8 bf16 = 4 VGPRs
typedef __attribute__((ext_vector_type(4))) float f32x4;

// fast gelu (tanh form): max abs dev from exact erf-gelu ~1e-3, threshold 2e-2
__device__ __forceinline__ float gelu_f(float x) {
    float s = 1.5957691216057308f * x * (1.0f + 0.044715f * x * x);
    float e = __expf(s);
    return x - x / (e + 1.0f);   // x*sigmoid(s); safe at +-inf
}

__device__ __forceinline__ ushort f2bf(float x) {
    uint u = __float_as_uint(x);
    return (ushort)((u + 0x7FFFu + ((u >> 16) & 1u)) >> 16);   // RNE
}
__device__ __forceinline__ uint pack2bf(float a, float b) {
    return (uint)f2bf(a) | ((uint)f2bf(b) << 16);
}
__device__ __forceinline__ float bf2f_lo(uint u) { return __uint_as_float(u << 16); }
__device__ __forceinline__ float bf2f_hi(uint u) { return __uint_as_float(u & 0xFFFF0000u); }

// conv tiling (shared by MFMA conv kernels)
#define TH2 8
#define TW2 64
#define NTX (WID / TW2)          // 6
#define NTY (HGT / TH2)          // 48
#define NBLK (NTX * NTY * BB)    // 1152
#define CHUNK (NBLK / 8)         // 144
#define HALO_H2 10
#define HALO_H3 11               // in3/in6: taps up to dh=3 (zero-weighted)
#define HALO_W2 66
#define CSTR 40   // padded ushort stride per pixel (80 B)

// wpack layout (ushorts):
//   0..4*9216      : 32->32 convs (rpA, rpB, fuA, fuB)
//   4*9216..6*9216 : 32->3 convs (rp_cout, fu_cout), rows>=3 zero
//   55296..58368   : 6->32 conv (fu_cin), k=tap*8+slot, K=96 (3 mfma)
//   58368..61440   : 3->32 conv (rp_cin), same k-map, slots 3..7 zero
#define WPK_IN6 55296
#define WPK_IN3 58368

// ---------------------------------------------------------------------------
// K-1: pack MFMA A-fragment tables (lane-linear bf16).
// ---------------------------------------------------------------------------
__global__ __launch_bounds__(256) void pack_wconv_kernel(
    const float* __restrict__ w0, const float* __restrict__ w1,
    const float* __restrict__ w2, const float* __restrict__ w3,
    const float* __restrict__ c0w, const float* __restrict__ c1w,
    const float* __restrict__ w6, const float* __restrict__ w7,
    ushort* __restrict__ wpk)
{
    const int layer = blockIdx.x;
    if (layer < 6) {
        const float* w = (layer == 0) ? w0 : (layer == 1) ? w1 :
                         (layer == 2) ? w2 : (layer == 3) ? w3 :
                         (layer == 4) ? c0w : c1w;
        const bool small = (layer >= 4);
        ushort* dst = wpk + layer * 9216;
        for (int i = threadIdx.x; i < 9216; i += 256) {
            const int j    = i & 7;
            const int lane = (i >> 3) & 63;
            const int half = (i >> 9) & 1;
            const int tap  = i >> 10;
            const int co = half * 16 + (lane & 15);
            const int ci = (lane >> 4) * 8 + j;
            float v = 0.f;
            if (!small || co < 3) v = w[co * 288 + ci * 9 + tap];
            dst[i] = f2bf(v);
        }
    } else {
        // layers 6 (in6) / 7 (in3): k = tap*8 + slot, K=96 (3 mfma x 2 halves)
        const bool is6 = (layer == 6);
        ushort* dst = wpk + (is6 ? WPK_IN6 : WPK_IN3);
        for (int i = threadIdx.x; i < 3072; i += 256) {
            const int j    = i & 7;
            const int lane = (i >> 3) & 63;
            const int c6   = i >> 9;          // 0..5
            const int m = c6 >> 1, half = c6 & 1;
            const int co = half * 16 + (lane & 15);
            const int k  = m * 32 + (lane >> 4) * 8 + j;
            const int tap = k >> 3, slot = k & 7;
            float v = 0.f;
            if (tap < 9) {
                if (is6) {
                    int ci = (slot < 3) ? slot : ((slot >= 4 && slot < 7) ? slot - 1 : -1);
                    if (ci >= 0) v = w6[co * 54 + ci * 9 + tap];
                } else {
                    if (slot < 3) v = w7[co * 27 + slot * 9 + tap];
                }
            }
            dst[i] = f2bf(v);
        }
    }
}

// ---------------------------------------------------------------------------
// K0: embedding-mean partial sums. grid (64, B).
// ---------------------------------------------------------------------------
__global__ __launch_bounds__(256) void emb_partial_kernel(
    const int* __restrict__ tokens, const float* __restrict__ emb,
    float* __restrict__ partial)
{
    const int s = blockIdx.x, b = blockIdx.y, tid = threadIdx.x;
    const int* tok = tokens + b * TT + s * 16;
    float acc = 0.f;
#pragma unroll
    for (int t = 0; t < 16; ++t) acc += emb[tok[t] * EE + tid];
    partial[(b * 64 + s) * EE + tid] = acc;
}

// ---------------------------------------------------------------------------
// K1: fused token head, latency-parallel.
// ---------------------------------------------------------------------------
__global__ __launch_bounds__(1024) void mlp_head_kernel(
    const float* __restrict__ partial,
    const float* __restrict__ aw1, const float* __restrict__ ab1,
    const float* __restrict__ aw2, const float* __restrict__ ab2,
    const float* __restrict__ lw1, const float* __restrict__ lb1,
    const float* __restrict__ gw1, const float* __restrict__ gb1,
    const float* __restrict__ gw2, const float* __restrict__ gb2,
    float* __restrict__ h3_out, float* __restrict__ lw_out)
{
    const int b = blockIdx.x;
    const int tid = threadIdx.x;
    const int o = tid & 255;
    const int q = tid >> 8;
    __shared__ float tf[256], h1[256], tf2s[256], h4[64], lg[8];
    __shared__ float red[4][256];

    {
        float acc = 0.f;
#pragma unroll
        for (int s = 0; s < 16; ++s)
            acc += partial[(b * 64 + q * 16 + s) * EE + o];
        red[q][o] = acc;
    }
    __syncthreads();
    if (tid < 256)
        tf[tid] = (red[0][tid] + red[1][tid] + red[2][tid] + red[3][tid]) * (1.0f / TT);
    __syncthreads();

    {
        float s = 0.f;
#pragma unroll 8
        for (int j = 0; j < 64; ++j) {
            const int k = (q << 6) + j;
            s += tf[k] * aw1[k * HIDD + o];
        }
        red[q][o] = s;
    }
    __syncthreads();
    if (tid < 256)
        h1[tid] = gelu_f(red[0][tid] + red[1][tid] + red[2][tid] + red[3][tid] + ab1[tid]);
    __syncthreads();

    {
        float s = 0.f;
#pragma unroll 8
        for (int j = 0; j < 64; ++j) {
            const int k = (q << 6) + j;
            s += h1[k] * aw2[k * HIDD + o];
        }
        red[q][o] = s;
    }
    __syncthreads();
    if (tid < 256)
        tf2s[tid] = red[0][tid] + red[1][tid] + red[2][tid] + red[3][tid] + ab2[tid];
    __syncthreads();

    {
        float s = 0.f;
#pragma unroll 8
        for (int j = 0; j < 64; ++j) {
            const int k = (q << 6) + j;
            s += tf2s[k] * lw1[k * HIDD + o];
        }
        red[q][o] = s;
    }
    __syncthreads();
    if (tid < 256)
        h3_out[b * HIDD + tid] =
            gelu_f(red[0][tid] + red[1][tid] + red[2][tid] + red[3][tid] + lb1[tid]);
    __syncthreads();

    {
        const int o64 = tid & 63, q16 = tid >> 6;
        float s = 0.f;
#pragma unroll
        for (int j = 0; j < 16; ++j) {
            const int k = q16 * 16 + j;
            s += tf2s[k] * gw1[k * 64 + o64];
        }
        ((float*)red)[q16 * 64 + o64] = s;
    }
    __syncthreads();
    if (tid < 64) {
        float s = gb1[tid];
#pragma unroll
        for (int r = 0; r < 16; ++r) s += ((float*)red)[r * 64 + tid];
        h4[tid] = gelu_f(s);
    }
    __syncthreads();

    if (tid < 8) {
        float s = gb2[tid];
#pragma unroll 8
        for (int k = 0; k < 64; ++k) s += h4[k] * gw2[k * LLUT + tid];
        lg[tid] = s;
    }
    __syncthreads();
    if (tid == 0) {
        float m = lg[0];
        for (int i = 1; i < LLUT; ++i) m = fmaxf(m, lg[i]);
        float ssum = 0.f, ex[LLUT];
        for (int i = 0; i < LLUT; ++i) { ex[i] = expf(lg[i] - m); ssum += ex[i]; }
        for (int i = 0; i < LLUT; ++i) lw_out[b * LLUT + i] = ex[i] / ssum;
    }
}

// ---------------------------------------------------------------------------
// K2: fused LUT-GEMM + softmax-combine -> clut (883 MB w2 stream).
// ---------------------------------------------------------------------------
__global__ __launch_bounds__(256) void lut_fused_kernel(
    const float* __restrict__ h3, const float* __restrict__ lwv,
    const float* __restrict__ w2, const float* __restrict__ b2,
    float* __restrict__ clut)
{
    __shared__ float h[BB * HIDD];
    __shared__ float lws[BB * LLUT];
    const int tid = threadIdx.x;
    for (int i = tid; i < BB * HIDD; i += 256) h[i] = h3[i];
    if (tid < BB * LLUT) lws[tid] = lwv[tid];
    __syncthreads();

    const int idx = blockIdx.x * 256 + tid;
    if (idx >= 3 * G3) return;
    const int c = idx / G3, v = idx - c * G3;

    float acc[BB][LLUT];
#pragma unroll
    for (int b = 0; b < BB; ++b)
#pragma unroll
        for (int l = 0; l < LLUT; ++l) acc[b][l] = 0.f;

    const float* wbase = w2 + (long)c * G3 + v;   // + l*3*G3 + k*NCOL
#pragma unroll 4
    for (int k = 0; k < HIDD; ++k) {
        const float* row = wbase + (long)k * NCOL;
        float wl[LLUT];
#pragma unroll
        for (int l = 0; l < LLUT; ++l) wl[l] = row[l * 3 * G3];
#pragma unroll
        for (int b = 0; b < BB; ++b) {
            const float hb = h[b * HIDD + k];
#pragma unroll
            for (int l = 0; l < LLUT; ++l) acc[b][l] += wl[l] * hb;
        }
    }

    float bb[LLUT];
#pragma unroll
    for (int l = 0; l < LLUT; ++l) bb[l] = b2[(long)(l * 3 + c) * G3 + v];

#pragma unroll
    for (int b = 0; b < BB; ++b) {
        float s = 0.f;
#pragma unroll
        for (int l = 0; l < LLUT; ++l) s += lws[b * LLUT + l] * (acc[b][l] + bb[l]);
        clut[(long)(b * 3 + c) * G3 + v] = s;
    }
}

// ---------------------------------------------------------------------------
// K5: MFMA 3->32 conv. img staged as bf16 [11][66][8] (slots 0..2 = ch,
// 3..7 = 0). k = tap*8+slot, 3 mfma x 2 halves; each B-frag = one b128.
// ---------------------------------------------------------------------------
__global__ __launch_bounds__(512) void conv_in3_mfma(
    const float* __restrict__ img, const ushort* __restrict__ wpk3,
    const float* __restrict__ bias, ushort* __restrict__ out)
{
    __shared__ ushort ihalo[HALO_H3 * HALO_W2 * 8];   // 11616 B
    __shared__ float s_bias[32];

    const int tid = threadIdx.x;
    const int bid = blockIdx.x;
    const int t   = (bid & 7) * CHUNK + (bid >> 3);
    const int tx  = t % NTX;
    const int rem = t / NTX;
    const int ty  = rem % NTY;
    const int b   = rem / NTY;
    const int h0 = ty * TH2;
    const int w0 = tx * TW2;

    if (tid < 32) s_bias[tid] = bias[tid];

    const float* imb = img + (long)b * 3 * HWPX;
    for (int i = tid; i < HALO_H3 * HALO_W2; i += 512) {
        const int row = i / HALO_W2, px = i - row * HALO_W2;
        const int gh = h0 + row - 1, gw = w0 + px - 1;
        float c0v = 0.f, c1v = 0.f, c2v = 0.f;
        if (gh >= 0 && gh < HGT && gw >= 0 && gw < WID) {
            const int p = gh * WID + gw;
            c0v = imb[p]; c1v = imb[HWPX + p]; c2v = imb[2 * HWPX + p];
        }
        uint4 u; u.x = pack2bf(c0v, c1v); u.y = pack2bf(c2v, 0.f);
        u.z = 0u; u.w = 0u;
        *(uint4*)(&ihalo[i * 8]) = u;
    }
    __syncthreads();

    const int lane = tid & 63, wid = tid >> 6;
    const int l15 = lane & 15, kg = lane >> 4;
    const int r = wid;
    const ushort* wl3 = wpk3 + lane * 8;

    f32x4 acc[4][2];
#pragma unroll
    for (int f = 0; f < 4; ++f)
#pragma unroll
        for (int cf = 0; cf < 2; ++cf)
            acc[f][cf] = (f32x4){0.f, 0.f, 0.f, 0.f};

#pragma unroll
    for (int m = 0; m < 3; ++m) {
        const int tap = m * 4 + kg;            // 0..11 (taps>=9 zero-weighted)
        const int dh = tap / 3, dwp = tap - 3 * (tap / 3);
        const bf16x8 a0 = *(const bf16x8*)(wl3 + (m * 2 + 0) * 512);
        const bf16x8 a1 = *(const bf16x8*)(wl3 + (m * 2 + 1) * 512);
#pragma unroll
        for (int f = 0; f < 4; ++f) {
            const int c0 = f * 16;
            const bf16x8 bv = *(const bf16x8*)(
                &ihalo[((r + dh) * HALO_W2 + (c0 + dwp + l15)) * 8]);
            acc[f][0] = __builtin_amdgcn_mfma_f32_16x16x32_bf16(a0, bv, acc[f][0], 0, 0, 0);
            acc[f][1] = __builtin_amdgcn_mfma_f32_16x16x32_bf16(a1, bv, acc[f][1], 0, 0, 0);
        }
    }

#pragma unroll
    for (int f = 0; f < 4; ++f) {
        const int c0 = f * 16;
        const long gpx = (long)b * HWPX + (long)(h0 + r) * WID + (w0 + c0 + l15);
#pragma unroll
        for (int cf = 0; cf < 2; ++cf) {
            const int co0 = cf * 16 + kg * 4;
            const float4 bv4 = *(const float4*)(&s_bias[co0]);
            uint2 o;
            o.x = pack2bf(gelu_f(acc[f][cf][0] + bv4.x), gelu_f(acc[f][cf][1] + bv4.y));
            o.y = pack2bf(gelu_f(acc[f][cf][2] + bv4.z), gelu_f(acc[f][cf][3] + bv4.w));
            *(uint2*)(out + gpx * 32 + co0) = o;
        }
    }
}

// ---------------------------------------------------------------------------
// K6: MFMA 32->32 conv (r14 measured-best structure).
// ---------------------------------------------------------------------------
template <bool HAS_RES>
__global__ __launch_bounds__(512, 6) void conv32_mfma(
    const ushort* __restrict__ in, const ushort* __restrict__ res,
    const ushort* __restrict__ wpk, const float* __restrict__ bias,
    const float* __restrict__ bn_g, const float* __restrict__ bn_bt,
    ushort* __restrict__ out)
{
    __shared__ ushort halo[HALO_H2 * HALO_W2 * CSTR];   // 52800 B
    __shared__ float s_scale[32], s_shift[32];

    const int tid = threadIdx.x;
    const int bid = blockIdx.x;
    const int t   = (bid & 7) * CHUNK + (bid >> 3);
    const int tx  = t % NTX;
    const int rem = t / NTX;
    const int ty  = rem % NTY;
    const int b   = rem / NTY;
    const int h0 = ty * TH2;
    const int w0 = tx * TW2;

    if (tid < 32) {
        float sg = bn_g[tid] * 0.9999950000375f;   // g*(1+1e-5)^-0.5
        s_scale[tid] = sg;
        s_shift[tid] = bias[tid] * sg + bn_bt[tid];
    }

    const ushort* inb = in + (long)b * HWPX * 32;
    for (int i = tid; i < HALO_H2 * HALO_W2 * 4; i += 512) {
        const int row = i / (HALO_W2 * 4);
        const int rem2 = i - row * (HALO_W2 * 4);
        const int px = rem2 >> 2, q = rem2 & 3;
        const int gh = h0 + row - 1, gw = w0 + px - 1;
        uint4 v = make_uint4(0u, 0u, 0u, 0u);
        if (gh >= 0 && gh < HGT && gw >= 0 && gw < WID)
            v = *(const uint4*)(inb + ((long)gh * WID + gw) * 32 + q * 8);
        *(uint4*)(&halo[(row * HALO_W2 + px) * CSTR + q * 8]) = v;
    }
    __syncthreads();

    const int lane = tid & 63, wid = tid >> 6;
    const int l15 = lane & 15, kg = lane >> 4;
    const int r = wid;
    const ushort* wlane = wpk + lane * 8;

    f32x4 acc[4][2];
#pragma unroll
    for (int f = 0; f < 4; ++f)
#pragma unroll
        for (int cf = 0; cf < 2; ++cf)
            acc[f][cf] = (f32x4){0.f, 0.f, 0.f, 0.f};

#pragma unroll
    for (int tap = 0; tap < 9; ++tap) {
        const int dh = tap / 3, dw = tap - dh * 3;
        const bf16x8 a0 = *(const bf16x8*)(wlane + (tap * 2 + 0) * 512);
        const bf16x8 a1 = *(const bf16x8*)(wlane + (tap * 2 + 1) * 512);
#pragma unroll
        for (int f = 0; f < 4; ++f) {
            const int c0 = f * 16;
            const bf16x8 bfv = *(const bf16x8*)(
                &halo[((r + dh) * HALO_W2 + (c0 + dw + l15)) * CSTR + kg * 8]);
            acc[f][0] = __builtin_amdgcn_mfma_f32_16x16x32_bf16(a0, bfv, acc[f][0], 0, 0, 0);
            acc[f][1] = __builtin_amdgcn_mfma_f32_16x16x32_bf16(a1, bfv, acc[f][1], 0, 0, 0);
        }
    }

#pragma unroll
    for (int f = 0; f < 4; ++f) {
        const int c0 = f * 16;
        const long gpx = (long)b * HWPX + (long)(h0 + r) * WID + (w0 + c0 + l15);
#pragma unroll
        for (int cf = 0; cf < 2; ++cf) {
            const int co0 = cf * 16 + kg * 4;
            const float4 sc = *(const float4*)(&s_scale[co0]);
            const float4 sh = *(const float4*)(&s_shift[co0]);
            float v0 = acc[f][cf][0] * sc.x + sh.x;
            float v1 = acc[f][cf][1] * sc.y + sh.y;
            float v2 = acc[f][cf][2] * sc.z + sh.z;
            float v3 = acc[f][cf][3] * sc.w + sh.w;
            if (HAS_RES) {
                const uint2 rv = *(const uint2*)(res + gpx * 32 + co0);
                v0 += bf2f_lo(rv.x); v1 += bf2f_hi(rv.x);
                v2 += bf2f_lo(rv.y); v3 += bf2f_hi(rv.y);
            }
            uint2 o;
            o.x = pack2bf(gelu_f(v0), gelu_f(v1));
            o.y = pack2bf(gelu_f(v2), gelu_f(v3));
            *(uint2*)(out + gpx * 32 + co0) = o;
        }
    }
}

// ---------------------------------------------------------------------------
// K7: MFMA 32->3 conv. FINAL=false additionally computes the trilinear LUT
// apply for its 512 tile pixels (1 px/thread) -> comb slots 0..3; conv
// result -> comb slots 4..7. FINAL=true: conv + img -> fp32 NCHW d_out.
// ---------------------------------------------------------------------------
template <bool FINAL>
__global__ __launch_bounds__(512, 4) void conv_out3_mfma(
    const ushort* __restrict__ in, const ushort* __restrict__ wpk,
    const float* __restrict__ bias, const float* __restrict__ img,
    float* __restrict__ outp, ushort* __restrict__ comb,
    const float* __restrict__ clut, const float* __restrict__ recon)
{
    __shared__ ushort halo[HALO_H2 * HALO_W2 * CSTR];   // 52800 B

    const int tid = threadIdx.x;
    const int bid = blockIdx.x;
    const int t   = (bid & 7) * CHUNK + (bid >> 3);
    const int tx  = t % NTX;
    const int rem = t / NTX;
    const int ty  = rem % NTY;
    const int b   = rem / NTY;
    const int h0 = ty * TH2;
    const int w0 = tx * TW2;

    const ushort* inb = in + (long)b * HWPX * 32;
    for (int i = tid; i < HALO_H2 * HALO_W2 * 4; i += 512) {
        const int row = i / (HALO_W2 * 4);
        const int rem2 = i - row * (HALO_W2 * 4);
        const int px = rem2 >> 2, q = rem2 & 3;
        const int gh = h0 + row - 1, gw = w0 + px - 1;
        uint4 v = make_uint4(0u, 0u, 0u, 0u);
        if (gh >= 0 && gh < HGT && gw >= 0 && gw < WID)
            v = *(const uint4*)(inb + ((long)gh * WID + gw) * 32 + q * 8);
        *(uint4*)(&halo[(row * HALO_W2 + px) * CSTR + q * 8]) = v;
    }
    __syncthreads();

    const int lane = tid & 63, wid = tid >> 6;
    const int l15 = lane & 15, kg = lane >> 4;
    const int r = wid;
    const ushort* wlane = wpk + lane * 8;

    f32x4 acc[4];
#pragma unroll
    for (int f = 0; f < 4; ++f) acc[f] = (f32x4){0.f, 0.f, 0.f, 0.f};

#pragma unroll
    for (int tap = 0; tap < 9; ++tap) {
        const int dh = tap / 3, dw = tap - dh * 3;
        const bf16x8 a0 = *(const bf16x8*)(wlane + (tap * 2 + 0) * 512);
#pragma unroll
        for (int f = 0; f < 4; ++f) {
            const int c0 = f * 16;
            const bf16x8 bfv = *(const bf16x8*)(
                &halo[((r + dh) * HALO_W2 + (c0 + dw + l15)) * CSTR + kg * 8]);
            acc[f] = __builtin_amdgcn_mfma_f32_16x16x32_bf16(a0, bfv, acc[f], 0, 0, 0);
        }
    }

    if (kg == 0) {   // rows 0..2 of D valid
        const float b0 = bias[0], b1 = bias[1], b2v = bias[2];
#pragma unroll
        for (int f = 0; f < 4; ++f) {
            const int p = (h0 + r) * WID + (w0 + f * 16 + l15);
            const long gpx = (long)b * HWPX + p;
            float v0 = acc[f][0] + b0;
            float v1 = acc[f][1] + b1;
            float v2 = acc[f][2] + b2v;
            if (FINAL) {
                outp[(long)(b * 3 + 0) * HWPX + p] = v0 + img[(long)(b * 3 + 0) * HWPX + p];
                outp[(long)(b * 3 + 1) * HWPX + p] = v1 + img[(long)(b * 3 + 1) * HWPX + p];
                outp[(long)(b * 3 + 2) * HWPX + p] = v2 + img[(long)(b * 3 + 2) * HWPX + p];
            } else {
                uint2 u;
                u.x = pack2bf(v0, v1);
                u.y = pack2bf(v2, 0.f);
                *(uint2*)(comb + gpx * 8 + 4) = u;
            }
        }
    }

    if (!FINAL) {
        // fused trilinear LUT apply: 1 px/thread over the 8x64 tile
        const int row = tid >> 6, col = tid & 63;
        const int p = (h0 + row) * WID + (w0 + col);
        const float* rc = recon + (long)b * 3 * HWPX;
        float cr = fminf(fmaxf(rc[p] * 32.f, 0.f), 32.f);
        float cg = fminf(fmaxf(rc[HWPX + p] * 32.f, 0.f), 32.f);
        float cb = fminf(fmaxf(rc[2 * HWPX + p] * 32.f, 0.f), 32.f);
        float fr = fminf(floorf(cr), 31.f);
        float fg = fminf(floorf(cg), 31.f);
        float fb = fminf(floorf(cb), 31.f);
        float tr = cr - fr, tg = cg - fg, tb_ = cb - fb;
        int idx = (((int)fr * GSZ + (int)fg) * GSZ + (int)fb);
        float c[3];
#pragma unroll
        for (int ch = 0; ch < 3; ++ch) {
            const float* lut = clut + (long)(b * 3 + ch) * G3;
            float v000 = lut[idx],                  v001 = lut[idx + 1];
            float v010 = lut[idx + GSZ],            v011 = lut[idx + GSZ + 1];
            float v100 = lut[idx + GSZ * GSZ],      v101 = lut[idx + GSZ * GSZ + 1];
            float v110 = lut[idx + GSZ * GSZ + GSZ], v111 = lut[idx + GSZ * GSZ + GSZ + 1];
            float c00 = v000 + (v001 - v000) * tb_;
            float c01 = v010 + (v011 - v010) * tb_;
            float c10 = v100 + (v101 - v100) * tb_;
            float c11 = v110 + (v111 - v110) * tb_;
            float c0 = c00 + (c01 - c00) * tg;
            float c1 = c10 + (c11 - c10) * tg;
            c[ch] = c0 + (c1 - c0) * tr;
        }
        uint2 u;
        u.x = pack2bf(c[0], c[1]);
        u.y = pack2bf(c[2], 0.f);
        *(uint2*)(comb + ((long)b * HWPX + p) * 8) = u;
    }
}

// ---------------------------------------------------------------------------
// K8: MFMA 6->32 conv. comb bf16 [px][8] staged to [11][66][8] LDS.
// k = tap*8+slot (K=96, 3 mfma x 2 halves); each B-frag = one b128 read.
// ---------------------------------------------------------------------------
__global__ __launch_bounds__(512) void conv_in6_mfma(
    const ushort* __restrict__ comb, const ushort* __restrict__ wpk6,
    const float* __restrict__ bias, ushort* __restrict__ out)
{
    __shared__ ushort chalo[HALO_H3 * HALO_W2 * 8];   // 11616 B
    __shared__ float s_bias[32];

    const int tid = threadIdx.x;
    const int bid = blockIdx.x;
    const int t   = (bid & 7) * CHUNK + (bid >> 3);
    const int tx  = t % NTX;
    const int rem = t / NTX;
    const int ty  = rem % NTY;
    const int b   = rem / NTY;
    const int h0 = ty * TH2;
    const int w0 = tx * TW2;

    if (tid < 32) s_bias[tid] = bias[tid];

    const ushort* cb = comb + (long)b * HWPX * 8;
    for (int i = tid; i < HALO_H3 * HALO_W2; i += 512) {
        const int row = i / HALO_W2, px = i - row * HALO_W2;
        const int gh = h0 + row - 1, gw = w0 + px - 1;
        uint4 v = make_uint4(0u, 0u, 0u, 0u);
        if (gh >= 0 && gh < HGT && gw >= 0 && gw < WID)
            v = *(const uint4*)(cb + ((long)gh * WID + gw) * 8);
        *(uint4*)(&chalo[i * 8]) = v;
    }
    __syncthreads();

    const int lane = tid & 63, wid = tid >> 6;
    const int l15 = lane & 15, kg = lane >> 4;
    const int r = wid;
    const ushort* wl6 = wpk6 + lane * 8;

    f32x4 acc[4][2];
#pragma unroll
    for (int f = 0; f < 4; ++f)
#pragma unroll
        for (int cf = 0; cf < 2; ++cf)
            acc[f][cf] = (f32x4){0.f, 0.f, 0.f, 0.f};

#pragma unroll
    for (int m = 0; m < 3; ++m) {
        const int tap = m * 4 + kg;            // 0..11 (taps>=9 zero-weighted)
        const int dh = tap / 3, dwp = tap - 3 * (tap / 3);
        const bf16x8 a0 = *(const bf16x8*)(wl6 + (m * 2 + 0) * 512);
        const bf16x8 a1 = *(const bf16x8*)(wl6 + (m * 2 + 1) * 512);
#pragma unroll
        for (int f = 0; f < 4; ++f) {
            const int c0 = f * 16;
            const bf16x8 bv = *(const bf16x8*)(
                &chalo[((r + dh) * HALO_W2 + (c0 + dwp + l15)) * 8]);
            acc[f][0] = __builtin_amdgcn_mfma_f32_16x16x32_bf16(a0, bv, acc[f][0], 0, 0, 0);
            acc[f][1] = __builtin_amdgcn_mfma_f32_16x16x32_bf16(a1, bv, acc[f][1], 0, 0, 0);
        }
    }

#pragma unroll
    for (int f = 0; f < 4; ++f) {
        const int c0 = f * 16;
        const long gpx = (long)b * HWPX + (long)(h0 + r) * WID + (w0 + c0 + l15);
#pragma unroll
        for (int cf = 0; cf < 2; ++cf) {
            const int co0 = cf * 16 + kg * 4;
            const float4 bv4 = *(const float4*)(&s_bias[co0]);
            uint2 o;
            o.x = pack2bf(gelu_f(acc[f][cf][0] + bv4.x), gelu_f(acc[f][cf][1] + bv4.y));
            o.y = pack2bf(gelu_f(acc[f][cf][2] + bv4.z), gelu_f(acc[f][cf][3] + bv4.w));
            *(uint2*)(out + gpx * 32 + co0) = o;
        }
    }
}

// ---------------------------------------------------------------------------
extern "C" void kernel_launch(void* const* d_in, const int* in_sizes, int n_in,
                              void* d_out, int out_size, void* d_ws, size_t ws_size,
                              hipStream_t stream)
{
    const int*   tokens  = (const int*)d_in[0];
    const float* img     = (const float*)d_in[1];
    const float* recon   = (const float*)d_in[2];
    const float* emb     = (const float*)d_in[3];
    const float* agg_w1  = (const float*)d_in[4];
    const float* agg_b1  = (const float*)d_in[5];
    const float* agg_w2  = (const float*)d_in[6];
    const float* agg_b2  = (const float*)d_in[7];
    const float* lut_w1  = (const float*)d_in[8];
    const float* lut_b1  = (const float*)d_in[9];
    const float* lut_w2  = (const float*)d_in[10];
    const float* lut_b2  = (const float*)d_in[11];
    const float* wg_w1   = (const float*)d_in[12];
    const float* wg_b1   = (const float*)d_in[13];
    const float* wg_w2   = (const float*)d_in[14];
    const float* wg_b2   = (const float*)d_in[15];
    const float* rp_cin_w = (const float*)d_in[16];
    const float* rp_cin_b = (const float*)d_in[17];
    const float* rp_rbA_w = (const float*)d_in[18];
    const float* rp_rbA_b = (const float*)d_in[19];
    const float* rp_rbA_g = (const float*)d_in[20];
    const float* rp_rbA_bt= (const float*)d_in[21];
    const float* rp_rbB_w = (const float*)d_in[22];
    const float* rp_rbB_b = (const float*)d_in[23];
    const float* rp_rbB_g = (const float*)d_in[24];
    const float* rp_rbB_bt= (const float*)d_in[25];
    const float* rp_cout_w= (const float*)d_in[26];
    const float* rp_cout_b= (const float*)d_in[27];
    const float* fu_cin_w = (const float*)d_in[28];
    const float* fu_cin_b = (const float*)d_in[29];
    const float* fu_rbA_w = (const float*)d_in[30];
    const float* fu_rbA_b = (const float*)d_in[31];
    const float* fu_rbA_g = (const float*)d_in[32];
    const float* fu_rbA_bt= (const float*)d_in[33];
    const float* fu_rbB_w = (const float*)d_in[34];
    const float* fu_rbB_b = (const float*)d_in[35];
    const float* fu_rbB_g = (const float*)d_in[36];
    const float* fu_rbB_bt= (const float*)d_in[37];
    const float* fu_cout_w= (const float*)d_in[38];
    const float* fu_cout_b= (const float*)d_in[39];

    float* ws = (float*)d_ws;
    float*  h3      = ws;                       // 1024
    float*  lwv     = ws + 1024;                // 32
    float*  partial = ws + 2048;                // 65536
    float*  clut    = ws + 69632;               // 431244
    ushort* wpack   = (ushort*)(ws + 524288);   // 61440 ushorts
    ushort* comb    = (ushort*)(ws + 589824);   // 4*HWPX*8 ushorts (bf16)
    ushort* act0    = (ushort*)(ws + 3145728);  // 18874368 ushorts
    ushort* act1    = (ushort*)(ws + 12582912);
    ushort* act2    = (ushort*)(ws + 22020096);
    float*  outp    = (float*)d_out;

    // pack all MFMA A-fragment tables
    pack_wconv_kernel<<<dim3(8), dim3(256), 0, stream>>>(
        rp_rbA_w, rp_rbB_w, fu_rbA_w, fu_rbB_w, rp_cout_w, fu_cout_w,
        fu_cin_w, rp_cin_w, wpack);

    // token head
    emb_partial_kernel<<<dim3(64, BB), dim3(256), 0, stream>>>(tokens, emb, partial);
    mlp_head_kernel<<<dim3(BB), dim3(1024), 0, stream>>>(
        partial, agg_w1, agg_b1, agg_w2, agg_b2,
        lut_w1, lut_b1, wg_w1, wg_b1, wg_w2, wg_b2, h3, lwv);

    // fused LUT GEMM + combine -> clut
    lut_fused_kernel<<<dim3((3 * G3 + 255) / 256), dim3(256), 0, stream>>>(
        h3, lwv, lut_w2, lut_b2, clut);

    const dim3 gm(NBLK), bm(512);

    // proc branch: img -> act0 -> act1 -> act2
    conv_in3_mfma<<<gm, bm, 0, stream>>>(img, wpack + WPK_IN3, rp_cin_b, act0);
    conv32_mfma<false><<<gm, bm, 0, stream>>>(
        act0, nullptr, wpack + 0 * 9216, rp_rbA_b, rp_rbA_g, rp_rbA_bt, act1);
    conv32_mfma<true><<<gm, bm, 0, stream>>>(
        act1, act0, wpack + 1 * 9216, rp_rbB_b, rp_rbB_g, rp_rbB_bt, act2);

    // proc 32->3 (MFMA) + fused LUT apply -> comb
    conv_out3_mfma<false><<<gm, bm, 0, stream>>>(
        act2, wpack + 4 * 9216, rp_cout_b, nullptr, nullptr, comb, clut, recon);

    // fuse branch: comb -> act0 -> act1 -> act2 -> d_out (+img)
    conv_in6_mfma<<<gm, bm, 0, stream>>>(comb, wpack + WPK_IN6, fu_cin_b, act0);
    conv32_mfma<false><<<gm, bm, 0, stream>>>(
        act0, nullptr, wpack + 2 * 9216, fu_rbA_b, fu_rbA_g, fu_rbA_bt, act1);
    conv32_mfma<true><<<gm, bm, 0, stream>>>(
        act1, act0, wpack + 3 * 9216, fu_rbB_b, fu_rbB_g, fu_rbB_bt, act2);
    conv_out3_mfma<true><<<gm, bm, 0, stream>>>(
        act2, wpack + 5 * 9216, fu_cout_b, img, outp, nullptr, nullptr, nullptr);
}